// Round 5
// baseline (41894.736 us; speedup 1.0000x reference)
//
#include <hip/hip_runtime.h>
#include <stdint.h>

#define SEQ 8192
#define EMB 1024
#define HID 2048
#define NCH 256

#define SCAN_B 64                   // persistent blocks (co-resident on 256 CUs)
#define SCAN_T 512                  // 8 waves/block
#define ROWS_PB (HID / SCAN_B)      // 32 rows of h per block (4 rows per wave)
#define SENT 0xFFFFFFFFu            // poison bit pattern: tanh never produces it

// ---------------------------------------------------------------------------
// Generic fp32 "TN" GEMM: C[m][n] = bias[n] + dot(X[m][:], W[n][:])
// ---------------------------------------------------------------------------
__global__ __launch_bounds__(256) void gemm_tn(const float* __restrict__ X,
                                               const float* __restrict__ W,
                                               const float* __restrict__ bias,
                                               float* __restrict__ C,
                                               int M, int N, int K)
{
    __shared__ float Xs[16][68];
    __shared__ float Ws[16][68];
    const int m0 = blockIdx.x * 64, n0 = blockIdx.y * 64;
    const int tid  = threadIdx.x;
    const int lrow = tid >> 2;
    const int kq   = (tid & 3) * 4;
    const int tx   = tid & 15, ty = tid >> 4;
    float acc[4][4] = {};
    const float* Xp = X + (size_t)(m0 + lrow) * K + kq;
    const float* Wp = W + (size_t)(n0 + lrow) * K + kq;

    for (int k0 = 0; k0 < K; k0 += 16) {
        float4 xv = *(const float4*)(Xp + k0);
        float4 wv = *(const float4*)(Wp + k0);
        __syncthreads();
        Xs[kq+0][lrow] = xv.x; Xs[kq+1][lrow] = xv.y;
        Xs[kq+2][lrow] = xv.z; Xs[kq+3][lrow] = xv.w;
        Ws[kq+0][lrow] = wv.x; Ws[kq+1][lrow] = wv.y;
        Ws[kq+2][lrow] = wv.z; Ws[kq+3][lrow] = wv.w;
        __syncthreads();
#pragma unroll
        for (int kk = 0; kk < 16; ++kk) {
            float4 av = *(const float4*)&Xs[kk][ty * 4];
            float4 bv = *(const float4*)&Ws[kk][tx * 4];
            float a[4] = {av.x, av.y, av.z, av.w};
            float b[4] = {bv.x, bv.y, bv.z, bv.w};
#pragma unroll
            for (int i = 0; i < 4; ++i)
#pragma unroll
                for (int j = 0; j < 4; ++j)
                    acc[i][j] += a[i] * b[j];
        }
    }
#pragma unroll
    for (int i = 0; i < 4; ++i) {
        const int m = m0 + ty * 4 + i;
#pragma unroll
        for (int j = 0; j < 4; ++j) {
            const int n = n0 + tx * 4 + j;
            C[(size_t)m * N + n] = acc[i][j] + bias[n];
        }
    }
}

// ---------------------------------------------------------------------------
// Persistent RNN scan, WAVE-AUTONOMOUS, barrier-free:
//   H rows 1..SEQ pre-poisoned 0xFFFFFFFF; producer lanes fire one relaxed
//   AGENT store per value (store IS the signal). Each wave needs the WHOLE
//   h row (its 16 subs tile all 2048 cols), so each wave stages its own 8KB
//   copy of H[t] into wave-private LDS:
//     fast path: 8 coalesced cacheable uint4 loads/lane (L1/L2 hits),
//     per-word poison check; stragglers re-fetched with 8B agent-scope
//     atomics (only pending chunks -> low L3 pressure) + s_sleep backoff.
//   NO __syncthreads in the loop: wave lockstep + in-order DS pipe make the
//   single 8KB/wave LDS buffer safe (step t+1's ds_writes issue only after
//   step t's ds_reads were consumed by FMAs).
// Thread (rl = tid>>4, sub = tid&15) owns row grow = b*32+rl, cols
//   col(j,e) = 64*j + 4*sub + e, j=0..31 -> 128 fp32 weights in regs/AGPRs.
// ---------------------------------------------------------------------------
__global__ __launch_bounds__(SCAN_T, 2) void rnn_scan(
    const int*  __restrict__ seq,
    const float* __restrict__ waa,
    const float* __restrict__ P,
    float* __restrict__ H)                 // (SEQ+1) x HID; row0 = 0, rest = SENT
{
    const int b    = blockIdx.x;
    const int tid  = threadIdx.x;
    const int wv   = tid >> 6;        // wave id 0..7
    const int lane = tid & 63;
    const int rl   = tid >> 4;        // 0..31
    const int sub  = tid & 15;        // 0..15
    const int grow = b * ROWS_PB + rl;

    __shared__ float lds[8][HID];     // 64 KB: one private row copy per wave

    // One-time weight load: 128 fp32 per thread.
    float w[128];
    {
        const float* wr = waa + (size_t)grow * HID + 4 * sub;
#pragma unroll
        for (int j = 0; j < 32; ++j) {
            float4 v = *(const float4*)(wr + 64 * j);
            w[4*j+0] = v.x; w[4*j+1] = v.y; w[4*j+2] = v.z; w[4*j+3] = v.w;
        }
    }
#pragma unroll
    for (int k = 0; k < 128; ++k) asm volatile("" : "+v"(w[k]));  // defeat remat

    unsigned* Hw = (unsigned*)H;

    for (int t = 0; t < SEQ; ++t) {
        // xa for this step (read-only, cached).
        const int ch = seq[t];
        float xav = 0.f;
        if (sub == 0) xav = P[(size_t)ch * HID + grow];

        // ---- stage H[t] into THIS WAVE's LDS copy, per-word validated ----
        const uint4* rowp = (const uint4*)(Hw + (size_t)t * HID);
        float* dst = &lds[wv][0];
        unsigned pend = 0;
        {
            uint4 v[8];
#pragma unroll
            for (int u = 0; u < 8; ++u)          // 8 coalesced 1KB wave-loads
                v[u] = rowp[lane + 64 * u];
#pragma unroll
            for (int u = 0; u < 8; ++u) {
                if (v[u].x != SENT && v[u].y != SENT &&
                    v[u].z != SENT && v[u].w != SENT)
                    *(uint4*)(dst + 4 * (lane + 64 * u)) = v[u];
                else
                    pend |= 1u << u;
            }
        }
        while (__ballot(pend != 0)) {
#pragma unroll
            for (int u = 0; u < 8; ++u) {
                if (pend & (1u << u)) {
                    const unsigned long long* p8 =
                        (const unsigned long long*)(rowp + (lane + 64 * u));
                    unsigned long long a = __hip_atomic_load(p8 + 0,
                        __ATOMIC_RELAXED, __HIP_MEMORY_SCOPE_AGENT);
                    unsigned long long c = __hip_atomic_load(p8 + 1,
                        __ATOMIC_RELAXED, __HIP_MEMORY_SCOPE_AGENT);
                    if ((unsigned)a != SENT && (unsigned)(a >> 32) != SENT &&
                        (unsigned)c != SENT && (unsigned)(c >> 32) != SENT) {
                        uint4 q;
                        q.x = (unsigned)a; q.y = (unsigned)(a >> 32);
                        q.z = (unsigned)c; q.w = (unsigned)(c >> 32);
                        *(uint4*)(dst + 4 * (lane + 64 * u)) = q;
                        pend &= ~(1u << u);
                    }
                }
            }
            if (pend) __builtin_amdgcn_s_sleep(1);   // back off only if still waiting
        }

        // ---- 128 FMAs from this wave's LDS copy (no barrier needed) ----
        float acc = 0.f;
        const float* hb = &lds[wv][4 * sub];
#pragma unroll
        for (int j = 0; j < 32; ++j) {
            float4 hv = *(const float4*)(hb + 64 * j);
            acc += w[4*j+0]*hv.x + w[4*j+1]*hv.y + w[4*j+2]*hv.z + w[4*j+3]*hv.w;
        }
#pragma unroll
        for (int off = 8; off > 0; off >>= 1)
            acc += __shfl_xor(acc, off, 16);

        if (sub == 0) {
            float hn = tanhf(xav + acc);
            __hip_atomic_store(Hw + (size_t)(t + 1) * HID + grow,
                               __float_as_uint(hn),
                               __ATOMIC_RELAXED, __HIP_MEMORY_SCOPE_AGENT);
        }
        // no drain / no flag / no barrier -- store IS the signal
    }
}

__global__ void copy_h(const float* __restrict__ src, float* __restrict__ dst)
{
    int i = blockIdx.x * blockDim.x + threadIdx.x;
    if (i < HID) dst[i] = src[i];
}

// ---------------------------------------------------------------------------
extern "C" void kernel_launch(void* const* d_in, const int* in_sizes, int n_in,
                              void* d_out, int out_size, void* d_ws, size_t ws_size,
                              hipStream_t stream)
{
    const int*   seq  = (const int*)  d_in[0];
    const float* emb  = (const float*)d_in[1];
    const float* wax  = (const float*)d_in[2];
    const float* waxb = (const float*)d_in[3];
    const float* waa  = (const float*)d_in[4];
    const float* wya  = (const float*)d_in[5];
    const float* wyab = (const float*)d_in[6];
    float* out = (float*)d_out;

    // ws layout: H[(SEQ+1)][HID] fp32 | P[NCH][HID] fp32
    float* H = (float*)d_ws;
    float* P = (float*)((char*)d_ws + (size_t)(SEQ + 1) * HID * sizeof(float));

    // Re-init every call: row 0 = h0 = 0; rows 1..SEQ = poison.
    hipMemsetAsync(H, 0, HID * sizeof(float), stream);
    hipMemsetAsync(H + HID, 0xFF, (size_t)SEQ * HID * sizeof(float), stream);

    // P = emb @ wax^T + wax_b   (M=256, N=2048, K=1024)
    dim3 gA(NCH / 64, HID / 64);
    gemm_tn<<<gA, 256, 0, stream>>>(emb, wax, waxb, P, NCH, HID, EMB);

    // Sequential recurrence (persistent, wave-autonomous, barrier-free).
    rnn_scan<<<SCAN_B, SCAN_T, 0, stream>>>(seq, waa, P, H);

    // out = H[1..SEQ] @ wya^T + wya_b   (M=8192, N=256, K=2048)
    dim3 gC(SEQ / 64, NCH / 64);
    gemm_tn<<<gC, 256, 0, stream>>>(H + HID, wya, wyab, out, SEQ, NCH, HID);

    // h_final = H[SEQ] -> tail of d_out
    copy_h<<<(HID + 255) / 256, 256, 0, stream>>>(H + (size_t)SEQ * HID,
                                                  out + (size_t)SEQ * NCH);
}

// Round 6
// 22763.014 us; speedup vs baseline: 1.8405x; 1.8405x over previous
//
#include <hip/hip_runtime.h>
#include <stdint.h>

#define SEQ 8192
#define EMB 1024
#define HID 2048
#define NCH 256

#define SCAN_B 64                   // persistent blocks (co-resident on 256 CUs)
#define SCAN_T 512                  // 8 waves/block
#define ROWS_PB (HID / SCAN_B)      // 32 rows of h per block (4 rows per wave)
#define SENT 0xFFFFFFFFu            // poison bit pattern: tanh never produces it

// ---------------------------------------------------------------------------
// Generic fp32 "TN" GEMM: C[m][n] = bias[n] + dot(X[m][:], W[n][:])
// ---------------------------------------------------------------------------
__global__ __launch_bounds__(256) void gemm_tn(const float* __restrict__ X,
                                               const float* __restrict__ W,
                                               const float* __restrict__ bias,
                                               float* __restrict__ C,
                                               int M, int N, int K)
{
    __shared__ float Xs[16][68];
    __shared__ float Ws[16][68];
    const int m0 = blockIdx.x * 64, n0 = blockIdx.y * 64;
    const int tid  = threadIdx.x;
    const int lrow = tid >> 2;
    const int kq   = (tid & 3) * 4;
    const int tx   = tid & 15, ty = tid >> 4;
    float acc[4][4] = {};
    const float* Xp = X + (size_t)(m0 + lrow) * K + kq;
    const float* Wp = W + (size_t)(n0 + lrow) * K + kq;

    for (int k0 = 0; k0 < K; k0 += 16) {
        float4 xv = *(const float4*)(Xp + k0);
        float4 wv = *(const float4*)(Wp + k0);
        __syncthreads();
        Xs[kq+0][lrow] = xv.x; Xs[kq+1][lrow] = xv.y;
        Xs[kq+2][lrow] = xv.z; Xs[kq+3][lrow] = xv.w;
        Ws[kq+0][lrow] = wv.x; Ws[kq+1][lrow] = wv.y;
        Ws[kq+2][lrow] = wv.z; Ws[kq+3][lrow] = wv.w;
        __syncthreads();
#pragma unroll
        for (int kk = 0; kk < 16; ++kk) {
            float4 av = *(const float4*)&Xs[kk][ty * 4];
            float4 bv = *(const float4*)&Ws[kk][tx * 4];
            float a[4] = {av.x, av.y, av.z, av.w};
            float b[4] = {bv.x, bv.y, bv.z, bv.w};
#pragma unroll
            for (int i = 0; i < 4; ++i)
#pragma unroll
                for (int j = 0; j < 4; ++j)
                    acc[i][j] += a[i] * b[j];
        }
    }
#pragma unroll
    for (int i = 0; i < 4; ++i) {
        const int m = m0 + ty * 4 + i;
#pragma unroll
        for (int j = 0; j < 4; ++j) {
            const int n = n0 + tx * 4 + j;
            C[(size_t)m * N + n] = acc[i][j] + bias[n];
        }
    }
}

// tanh(x) = 1 - 2/(exp2(x*2*log2e)+1); exact at +-inf, ~1e-6 rel error.
__device__ __forceinline__ float fast_tanh(float x)
{
    float e = __builtin_amdgcn_exp2f(x * 2.885390081777927f); // 2*log2(e)
    return 1.0f - 2.0f * __builtin_amdgcn_rcpf(e + 1.0f);
}

// ---------------------------------------------------------------------------
// Persistent RNN scan. R4 protocol (block-shared staging, one-hop poison
// sync, single barrier, parity LDS) + register-blocked compute:
//   wave wv owns rows R0 = b*32+4*wv .. R0+3; lane l owns cols
//   {256j + 4l + e : j=0..7, e=0..3} -> 128 weights in regs, but each LDS
//   float4 is used for 4 rows -> 8 ds_read_b128/lane/step (was 32).
//   Paired butterfly (10 shuffles) leaves row (l&3)'s sum in lane l;
//   lanes 0..3 tanh + publish 4 contiguous dwords (one store instr).
// ---------------------------------------------------------------------------
__global__ __launch_bounds__(SCAN_T, 2) void rnn_scan(
    const int*  __restrict__ seq,
    const float* __restrict__ waa,
    const float* __restrict__ P,
    float* __restrict__ H)                 // (SEQ+1) x HID; row0 = 0, rest = SENT
{
    const int b    = blockIdx.x;
    const int tid  = threadIdx.x;
    const int wv   = tid >> 6;        // wave id 0..7
    const int lane = tid & 63;
    const int R0   = b * ROWS_PB + wv * 4;   // first of this wave's 4 rows

    __shared__ float hbuf[2][HID];    // 16 KB parity double-buffer

    // One-time weight load: w[i][4j+e] = waa[R0+i][256j+4*lane+e].
    float w0[32], w1[32], w2[32], w3[32];
#pragma unroll
    for (int j = 0; j < 8; ++j) {
        const float* base = waa + 256 * j + 4 * lane;
        float4 a = *(const float4*)(base + (size_t)(R0 + 0) * HID);
        float4 c = *(const float4*)(base + (size_t)(R0 + 1) * HID);
        float4 d = *(const float4*)(base + (size_t)(R0 + 2) * HID);
        float4 e = *(const float4*)(base + (size_t)(R0 + 3) * HID);
        w0[4*j+0]=a.x; w0[4*j+1]=a.y; w0[4*j+2]=a.z; w0[4*j+3]=a.w;
        w1[4*j+0]=c.x; w1[4*j+1]=c.y; w1[4*j+2]=c.z; w1[4*j+3]=c.w;
        w2[4*j+0]=d.x; w2[4*j+1]=d.y; w2[4*j+2]=d.z; w2[4*j+3]=d.w;
        w3[4*j+0]=e.x; w3[4*j+1]=e.y; w3[4*j+2]=e.z; w3[4*j+3]=e.w;
    }
#pragma unroll
    for (int k = 0; k < 32; ++k) {
        asm volatile("" : "+v"(w0[k])); asm volatile("" : "+v"(w1[k]));
        asm volatile("" : "+v"(w2[k])); asm volatile("" : "+v"(w3[k]));
    }

    unsigned* Hw = (unsigned*)H;

    for (int t = 0; t < SEQ; ++t) {
        // xa for this step: only lanes 0..3 need P[ch][R0+lane] (overlaps poll).
        const int ch = seq[t];
        float xav = 0.f;
        if (lane < 4) xav = P[(size_t)ch * HID + R0 + lane];

        // --- stage my 4 words of H[t] into block-shared LDS (R4 protocol) ---
        {
            const unsigned* p = Hw + (size_t)t * HID + tid * 4;
            uint4 v = *(const uint4*)p;                 // cacheable fast path
            if (v.x == SENT || v.y == SENT || v.z == SENT || v.w == SENT) {
                const unsigned long long* p8 = (const unsigned long long*)p;
                for (;;) {
                    unsigned long long a = __hip_atomic_load(p8 + 0,
                        __ATOMIC_RELAXED, __HIP_MEMORY_SCOPE_AGENT);
                    unsigned long long c = __hip_atomic_load(p8 + 1,
                        __ATOMIC_RELAXED, __HIP_MEMORY_SCOPE_AGENT);
                    if ((unsigned)a != SENT && (unsigned)(a >> 32) != SENT &&
                        (unsigned)c != SENT && (unsigned)(c >> 32) != SENT) {
                        v.x = (unsigned)a; v.y = (unsigned)(a >> 32);
                        v.z = (unsigned)c; v.w = (unsigned)(c >> 32);
                        break;
                    }
                    __builtin_amdgcn_s_sleep(1);
                }
            }
            *(uint4*)&hbuf[t & 1][tid * 4] = v;
        }
        __syncthreads();

        // --- 8 conflict-free b128 reads, 128 FMAs over 4 rows ---
        float a0 = 0.f, a1 = 0.f, a2 = 0.f, a3 = 0.f;
        const float* hb = &hbuf[t & 1][4 * lane];
#pragma unroll
        for (int j = 0; j < 8; ++j) {
            float4 hv = *(const float4*)(hb + 256 * j);
            a0 += w0[4*j+0]*hv.x + w0[4*j+1]*hv.y + w0[4*j+2]*hv.z + w0[4*j+3]*hv.w;
            a1 += w1[4*j+0]*hv.x + w1[4*j+1]*hv.y + w1[4*j+2]*hv.z + w1[4*j+3]*hv.w;
            a2 += w2[4*j+0]*hv.x + w2[4*j+1]*hv.y + w2[4*j+2]*hv.z + w2[4*j+3]*hv.w;
            a3 += w3[4*j+0]*hv.x + w3[4*j+1]*hv.y + w3[4*j+2]*hv.z + w3[4*j+3]*hv.w;
        }
        // Paired butterfly: row (lane&3)'s full sum ends in lane l.
        a0 += __shfl_xor(a0, 1, 64);
        a1 += __shfl_xor(a1, 1, 64);
        a2 += __shfl_xor(a2, 1, 64);
        a3 += __shfl_xor(a3, 1, 64);
        float m01 = (lane & 1) ? a1 : a0;
        float m23 = (lane & 1) ? a3 : a2;
        m01 += __shfl_xor(m01, 2, 64);
        m23 += __shfl_xor(m23, 2, 64);
        float m = (lane & 2) ? m23 : m01;
        m += __shfl_xor(m, 4, 64);
        m += __shfl_xor(m, 8, 64);
        m += __shfl_xor(m, 16, 64);
        m += __shfl_xor(m, 32, 64);

        if (lane < 4) {
            float hn = fast_tanh(xav + m);
            __hip_atomic_store(Hw + (size_t)(t + 1) * HID + R0 + lane,
                               __float_as_uint(hn),
                               __ATOMIC_RELAXED, __HIP_MEMORY_SCOPE_AGENT);
        }
        // no drain / no flag / no trailing barrier -- store IS the signal
    }
}

__global__ void copy_h(const float* __restrict__ src, float* __restrict__ dst)
{
    int i = blockIdx.x * blockDim.x + threadIdx.x;
    if (i < HID) dst[i] = src[i];
}

// ---------------------------------------------------------------------------
extern "C" void kernel_launch(void* const* d_in, const int* in_sizes, int n_in,
                              void* d_out, int out_size, void* d_ws, size_t ws_size,
                              hipStream_t stream)
{
    const int*   seq  = (const int*)  d_in[0];
    const float* emb  = (const float*)d_in[1];
    const float* wax  = (const float*)d_in[2];
    const float* waxb = (const float*)d_in[3];
    const float* waa  = (const float*)d_in[4];
    const float* wya  = (const float*)d_in[5];
    const float* wyab = (const float*)d_in[6];
    float* out = (float*)d_out;

    // ws layout: H[(SEQ+1)][HID] fp32 | P[NCH][HID] fp32
    float* H = (float*)d_ws;
    float* P = (float*)((char*)d_ws + (size_t)(SEQ + 1) * HID * sizeof(float));

    // Re-init every call: row 0 = h0 = 0; rows 1..SEQ = poison.
    hipMemsetAsync(H, 0, HID * sizeof(float), stream);
    hipMemsetAsync(H + HID, 0xFF, (size_t)SEQ * HID * sizeof(float), stream);

    // P = emb @ wax^T + wax_b   (M=256, N=2048, K=1024)
    dim3 gA(NCH / 64, HID / 64);
    gemm_tn<<<gA, 256, 0, stream>>>(emb, wax, waxb, P, NCH, HID, EMB);

    // Sequential recurrence (persistent, one-hop poison sync).
    rnn_scan<<<SCAN_B, SCAN_T, 0, stream>>>(seq, waa, P, H);

    // out = H[1..SEQ] @ wya^T + wya_b   (M=8192, N=256, K=2048)
    dim3 gC(SEQ / 64, NCH / 64);
    gemm_tn<<<gC, 256, 0, stream>>>(H + HID, wya, wyab, out, SEQ, NCH, HID);

    // h_final = H[SEQ] -> tail of d_out
    copy_h<<<(HID + 255) / 256, 256, 0, stream>>>(H + (size_t)SEQ * HID,
                                                  out + (size_t)SEQ * NCH);
}

// Round 10
// 15592.863 us; speedup vs baseline: 2.6868x; 1.4598x over previous
//
#include <hip/hip_runtime.h>
#include <stdint.h>

#define SEQ 8192
#define EMB 1024
#define HID 2048
#define NCH 256

#define SCAN_B 64                   // persistent blocks (co-resident, proven R1-R6)
#define SCAN_T 512                  // 8 waves/block
#define ROWS_PB (HID / SCAN_B)      // 32 rows per block (4 per wave)
#define SENT 0xFFFFFFFFu            // poison: tanh never produces this pattern
#define NREP 4                      // ring replicas (spread L3 line ownership)
#define NSLOT 8                     // ring slots (skew<=1 proven; margin 4)

typedef unsigned uint4v __attribute__((ext_vector_type(4)));

// ---------------------------------------------------------------------------
// Generic fp32 "TN" GEMM: C[m][n] = bias[n] + dot(X[m][:], W[n][:])
// ---------------------------------------------------------------------------
__global__ __launch_bounds__(256) void gemm_tn(const float* __restrict__ X,
                                               const float* __restrict__ W,
                                               const float* __restrict__ bias,
                                               float* __restrict__ C,
                                               int M, int N, int K)
{
    __shared__ float Xs[16][68];
    __shared__ float Ws[16][68];
    const int m0 = blockIdx.x * 64, n0 = blockIdx.y * 64;
    const int tid  = threadIdx.x;
    const int lrow = tid >> 2;
    const int kq   = (tid & 3) * 4;
    const int tx   = tid & 15, ty = tid >> 4;
    float acc[4][4] = {};
    const float* Xp = X + (size_t)(m0 + lrow) * K + kq;
    const float* Wp = W + (size_t)(n0 + lrow) * K + kq;

    for (int k0 = 0; k0 < K; k0 += 16) {
        float4 xv = *(const float4*)(Xp + k0);
        float4 wv = *(const float4*)(Wp + k0);
        __syncthreads();
        Xs[kq+0][lrow] = xv.x; Xs[kq+1][lrow] = xv.y;
        Xs[kq+2][lrow] = xv.z; Xs[kq+3][lrow] = xv.w;
        Ws[kq+0][lrow] = wv.x; Ws[kq+1][lrow] = wv.y;
        Ws[kq+2][lrow] = wv.z; Ws[kq+3][lrow] = wv.w;
        __syncthreads();
#pragma unroll
        for (int kk = 0; kk < 16; ++kk) {
            float4 av = *(const float4*)&Xs[kk][ty * 4];
            float4 bv = *(const float4*)&Ws[kk][tx * 4];
            float a[4] = {av.x, av.y, av.z, av.w};
            float b[4] = {bv.x, bv.y, bv.z, bv.w};
#pragma unroll
            for (int i = 0; i < 4; ++i)
#pragma unroll
                for (int j = 0; j < 4; ++j)
                    acc[i][j] += a[i] * b[j];
        }
    }
#pragma unroll
    for (int i = 0; i < 4; ++i) {
        const int m = m0 + ty * 4 + i;
#pragma unroll
        for (int j = 0; j < 4; ++j) {
            const int n = n0 + tx * 4 + j;
            C[(size_t)m * N + n] = acc[i][j] + bias[n];
        }
    }
}

// tanh(x) = 1 - 2/(exp2(2x*log2e)+1); ~1e-6 rel error, finite everywhere.
__device__ __forceinline__ float fast_tanh(float x)
{
    float e = __builtin_amdgcn_exp2f(x * 2.885390081777927f);
    return 1.0f - 2.0f * __builtin_amdgcn_rcpf(e + 1.0f);
}

// ---------------------------------------------------------------------------
// Persistent RNN scan (R6 compute, ring-replicated exchange):
//   Exchange lives in a tiny ring: ring[rep][slot][HID], rep=0..3, slot=t&7.
//   Producers (lanes 0-3 of each wave, 1 row each) write their h value to all
//   4 replicas of slot (t+1)&7 (relaxed AGENT stores -> coherence point),
//   plus one plain store to H[t+1] (read only by the epilogue GEMM), plus
//   re-poison slot (t+5)&7. Consumers poll replica (blockIdx&3) only ->
//   16 reader-blocks per 64B line instead of 64, and the whole polled set is
//   256 KB (L3-resident). Block skew is provably <=1 step (a block enters
//   step t+1 only after row t is complete, i.e. after ALL blocks finished
//   producing during step t), so slot reuse at distance 8 with poison at
//   distance 4 is race-free. Slot 0 of each replica is pre-zeroed (h0 = 0);
//   all other slots pre-poisoned.
//   Compute identical to R6 (proven): wave owns 4 rows, lane l covers cols
//   {256j+4l..+3}, 128 fp32 weights in regs, paired butterfly reduce.
// ---------------------------------------------------------------------------
__global__ __launch_bounds__(SCAN_T, 2) void rnn_scan(
    const int*  __restrict__ seq,
    const float* __restrict__ waa,
    const float* __restrict__ P,
    float* __restrict__ H,                 // (SEQ+1) x HID; plain (not polled)
    unsigned* __restrict__ ring)           // NREP x NSLOT x HID
{
    const int b    = blockIdx.x;
    const int tid  = threadIdx.x;
    const int wv   = tid >> 6;        // wave id 0..7
    const int lane = tid & 63;
    const int R0   = b * ROWS_PB + wv * 4;   // first of this wave's 4 rows
    const int rep  = b & (NREP - 1);

    __shared__ float hbuf[2][HID];    // 16 KB parity double-buffer

    // One-time weight load: w[i][4j+e] = waa[R0+i][256j+4*lane+e].
    float w0[32], w1[32], w2[32], w3[32];
#pragma unroll
    for (int j = 0; j < 8; ++j) {
        const float* base = waa + 256 * j + 4 * lane;
        float4 a = *(const float4*)(base + (size_t)(R0 + 0) * HID);
        float4 c = *(const float4*)(base + (size_t)(R0 + 1) * HID);
        float4 d = *(const float4*)(base + (size_t)(R0 + 2) * HID);
        float4 e = *(const float4*)(base + (size_t)(R0 + 3) * HID);
        w0[4*j+0]=a.x; w0[4*j+1]=a.y; w0[4*j+2]=a.z; w0[4*j+3]=a.w;
        w1[4*j+0]=c.x; w1[4*j+1]=c.y; w1[4*j+2]=c.z; w1[4*j+3]=c.w;
        w2[4*j+0]=d.x; w2[4*j+1]=d.y; w2[4*j+2]=d.z; w2[4*j+3]=d.w;
        w3[4*j+0]=e.x; w3[4*j+1]=e.y; w3[4*j+2]=e.z; w3[4*j+3]=e.w;
    }
#pragma unroll
    for (int k = 0; k < 32; ++k) {
        asm volatile("" : "+v"(w0[k])); asm volatile("" : "+v"(w1[k]));
        asm volatile("" : "+v"(w2[k])); asm volatile("" : "+v"(w3[k]));
    }

    unsigned* myring = ring + (size_t)rep * NSLOT * HID;

    for (int t = 0; t < SEQ; ++t) {
        // xa for this step (read-only, cached) -- overlaps the poll.
        const int ch = seq[t];
        float xav = 0.f;
        if (lane < 4) xav = P[(size_t)ch * HID + R0 + lane];

        // --- poll my 4 words of slot t&7 (agent-scope, R4-proven loop) ---
        {
            const unsigned long long* p8 = (const unsigned long long*)
                (myring + (size_t)(t & (NSLOT - 1)) * HID + tid * 4);
            unsigned long long a = __hip_atomic_load(p8 + 0, __ATOMIC_RELAXED,
                                                     __HIP_MEMORY_SCOPE_AGENT);
            unsigned long long c = __hip_atomic_load(p8 + 1, __ATOMIC_RELAXED,
                                                     __HIP_MEMORY_SCOPE_AGENT);
            while (((unsigned)a == SENT) || ((unsigned)(a >> 32) == SENT) ||
                   ((unsigned)c == SENT) || ((unsigned)(c >> 32) == SENT)) {
                __builtin_amdgcn_s_sleep(1);
                a = __hip_atomic_load(p8 + 0, __ATOMIC_RELAXED,
                                      __HIP_MEMORY_SCOPE_AGENT);
                c = __hip_atomic_load(p8 + 1, __ATOMIC_RELAXED,
                                      __HIP_MEMORY_SCOPE_AGENT);
            }
            uint4v v;
            v.x = (unsigned)a; v.y = (unsigned)(a >> 32);
            v.z = (unsigned)c; v.w = (unsigned)(c >> 32);
            *(uint4v*)&hbuf[t & 1][tid * 4] = v;
        }
        __syncthreads();

        // --- 8 conflict-free b128 reads, 128 FMAs over 4 rows (R6) ---
        float a0 = 0.f, a1 = 0.f, a2 = 0.f, a3 = 0.f;
        const float* hb = &hbuf[t & 1][4 * lane];
#pragma unroll
        for (int j = 0; j < 8; ++j) {
            float4 hv = *(const float4*)(hb + 256 * j);
            a0 += w0[4*j+0]*hv.x + w0[4*j+1]*hv.y + w0[4*j+2]*hv.z + w0[4*j+3]*hv.w;
            a1 += w1[4*j+0]*hv.x + w1[4*j+1]*hv.y + w1[4*j+2]*hv.z + w1[4*j+3]*hv.w;
            a2 += w2[4*j+0]*hv.x + w2[4*j+1]*hv.y + w2[4*j+2]*hv.z + w2[4*j+3]*hv.w;
            a3 += w3[4*j+0]*hv.x + w3[4*j+1]*hv.y + w3[4*j+2]*hv.z + w3[4*j+3]*hv.w;
        }
        // Paired butterfly: row (lane&3)'s full sum ends in lane l.
        a0 += __shfl_xor(a0, 1, 64);
        a1 += __shfl_xor(a1, 1, 64);
        a2 += __shfl_xor(a2, 1, 64);
        a3 += __shfl_xor(a3, 1, 64);
        float m01 = (lane & 1) ? a1 : a0;
        float m23 = (lane & 1) ? a3 : a2;
        m01 += __shfl_xor(m01, 2, 64);
        m23 += __shfl_xor(m23, 2, 64);
        float m = (lane & 2) ? m23 : m01;
        m += __shfl_xor(m, 4, 64);
        m += __shfl_xor(m, 8, 64);
        m += __shfl_xor(m, 16, 64);
        m += __shfl_xor(m, 32, 64);

        if (lane < 4) {
            float hn = fast_tanh(xav + m);
            const unsigned hu = __float_as_uint(hn);
            const int row = R0 + lane;
            const int s1 = (t + 1) & (NSLOT - 1);
            const int s5 = (t + 5) & (NSLOT - 1);
#pragma unroll
            for (int r = 0; r < NREP; ++r) {
                unsigned* rb = ring + (size_t)r * NSLOT * HID;
                __hip_atomic_store(rb + (size_t)s1 * HID + row, hu,
                                   __ATOMIC_RELAXED, __HIP_MEMORY_SCOPE_AGENT);
                __hip_atomic_store(rb + (size_t)s5 * HID + row, SENT,
                                   __ATOMIC_RELAXED, __HIP_MEMORY_SCOPE_AGENT);
            }
            H[(size_t)(t + 1) * HID + row] = hn;   // epilogue GEMM input
        }
        // store IS the signal; unique addresses per slot -> race-free
    }
}

__global__ void copy_h(const float* __restrict__ src, float* __restrict__ dst)
{
    int i = blockIdx.x * blockDim.x + threadIdx.x;
    if (i < HID) dst[i] = src[i];
}

// ---------------------------------------------------------------------------
extern "C" void kernel_launch(void* const* d_in, const int* in_sizes, int n_in,
                              void* d_out, int out_size, void* d_ws, size_t ws_size,
                              hipStream_t stream)
{
    const int*   seq  = (const int*)  d_in[0];
    const float* emb  = (const float*)d_in[1];
    const float* wax  = (const float*)d_in[2];
    const float* waxb = (const float*)d_in[3];
    const float* waa  = (const float*)d_in[4];
    const float* wya  = (const float*)d_in[5];
    const float* wyab = (const float*)d_in[6];
    float* out = (float*)d_out;

    // ws layout: H[(SEQ+1)][HID] fp32 | P[NCH][HID] fp32 | ring[4][8][HID] u32
    float*    H    = (float*)d_ws;
    float*    P    = (float*)((char*)d_ws + (size_t)(SEQ + 1) * HID * sizeof(float));
    unsigned* ring = (unsigned*)(P + (size_t)NCH * HID);

    // Re-init every call: ring all-poison, then slot 0 of each replica = h0 = 0.
    (void)hipMemsetAsync(ring, 0xFF, (size_t)NREP * NSLOT * HID * sizeof(unsigned), stream);
    for (int r = 0; r < NREP; ++r)
        (void)hipMemsetAsync(ring + (size_t)r * NSLOT * HID, 0,
                             HID * sizeof(unsigned), stream);

    // P = emb @ wax^T + wax_b   (M=256, N=2048, K=1024)
    dim3 gA(NCH / 64, HID / 64);
    gemm_tn<<<gA, 256, 0, stream>>>(emb, wax, waxb, P, NCH, HID, EMB);

    // Sequential recurrence (persistent, ring-replicated poison sync).
    rnn_scan<<<SCAN_B, SCAN_T, 0, stream>>>(seq, waa, P, H, ring);

    // out = H[1..SEQ] @ wya^T + wya_b   (M=8192, N=256, K=2048)
    dim3 gC(SEQ / 64, NCH / 64);
    gemm_tn<<<gC, 256, 0, stream>>>(H + HID, wya, wyab, out, SEQ, NCH, HID);

    // h_final = H[SEQ] -> tail of d_out
    copy_h<<<(HID + 255) / 256, 256, 0, stream>>>(H + (size_t)SEQ * HID,
                                                  out + (size_t)SEQ * NCH);
}